// Round 2
// baseline (1534.083 us; speedup 1.0000x reference)
//
#include <hip/hip_runtime.h>
#include <math.h>

// CPQuadRankLayer: B=16, N=2048, IN=OUT=256, R=64, Q=4.
// out[b,n,o] = sum_r ( prod_q rmsnorm_r(x[b,n,q,:] @ Fq[n]^T) )[r] * gain[n] * Fo[n,r,o]
//              + mean_q x[b,n,q,o]
//
// One WG per n, 512 threads, 72.3 KB LDS -> 2 WG/CU (the round-1 kernel was
// 1 WG/CU and its serial sections left HBM idle ~45% of each round).
// Factor stream: 20 x 16KB slabs per n (16 proj i16-slices + 4 fo quarters)
// through a 3-slot LDS ring via global_load_lds(16B); x as 4KB i16 chunks in a
// 2-slot buffer. Counted vmcnt (never 0 in the loop), raw s_barrier.

#define WAITVM(NLIT) asm volatile("s_waitcnt vmcnt(" #NLIT ") lgkmcnt(0)" ::: "memory")
#define LGKM0()      asm volatile("s_waitcnt lgkmcnt(0)" ::: "memory")
#define BARRIER()    __builtin_amdgcn_s_barrier()

__device__ __forceinline__ void g2l16(const float* g, float* l) {
  __builtin_amdgcn_global_load_lds(
      (const __attribute__((address_space(1))) void*)g,
      (__attribute__((address_space(3))) void*)l, 16, 0, 0);
}

#define NN 2048

__global__ __launch_bounds__(512, 4) void cpquad_kernel(
    const float* __restrict__ x,
    const float* __restrict__ ftl, const float* __restrict__ ftr,
    const float* __restrict__ fbl, const float* __restrict__ fbr,
    const float* __restrict__ fout, const float* __restrict__ gain,
    float* __restrict__ out) {

  // LDS: 12288 + 2048 + 4096 + 64 floats = 72.25 KB
  alignas(16) __shared__ float s_fb[3 * 4096]; // ring: proj slab [4q][64r][16i] / fo quarter [16r][256o]
  alignas(16) __shared__ float s_xs[2 * 1024]; // x i16 chunk dbuf: [64 c2=b*4+q][16 i]
  alignas(16) __shared__ float s_ps[4096];     // [4 q][16 b][64 r]; plane0 overwritten by merged
  __shared__ float s_rr[64];                   // [4 q][16 b] 1/rms

  const int t = threadIdx.x, lane = t & 63, wid = t >> 6;
  const int n = blockIdx.x;
  const float gn = gain[n];

  // ---------- staging sources ----------
  // proj slab chunk k2 (1KB, 64 lanes x 16B): c = wid*2+k2; q=c>>2; r=(c&3)*16+(lane>>2)
  const float* ss[2];
#pragma unroll
  for (int k2 = 0; k2 < 2; ++k2) {
    const int c = wid * 2 + k2, q = c >> 2, r = (c & 3) * 16 + (lane >> 2);
    const float* fq = (q == 0) ? ftl : ((q == 1) ? ftr : ((q == 2) ? fbl : fbr));
    ss[k2] = fq + ((size_t)n * 64 + r) * 256 + (lane & 3) * 4;
  }
  // x chunk (waves 0-3 only, 1KB): c2 = wid*16 + (lane>>2); b=c2>>2; qx=c2&3
  const int c2 = wid * 16 + (lane >> 2);
  const float* xsrc =
      x + (((size_t)(c2 >> 2) * NN + n) * 4 + (c2 & 3)) * 256 + (lane & 3) * 4;
  // fo quarter chunk k2: linear [16r][256o]
  const float* osrc = fout + (size_t)n * 16384 + wid * 512 + lane * 4;

  // ---------- issue helpers (wave-uniform LDS base; HW scatters lane*16B) ----------
  auto ISSUE_SLAB = [&](int s) {
    float* d = s_fb + (s % 3) * 4096 + wid * 512;
    g2l16(ss[0] + s * 16, d);
    g2l16(ss[1] + s * 16, d + 256);
  };
  auto ISSUE_X = [&](int p) {
    if (wid < 4) g2l16(xsrc + p * 16, s_xs + (p & 1) * 1024 + wid * 256);
  };
  auto ISSUE_FO = [&](int h) {
    float* d = s_fb + ((16 + h) % 3) * 4096 + wid * 512;
    g2l16(osrc + h * 4096, d);
    g2l16(osrc + h * 4096 + 256, d + 256);
  };

  // ---------- prologue: X0, S0, S1 (order matters for vmcnt counting) ----------
  ISSUE_X(0);
  ISSUE_SLAB(0);
  ISSUE_SLAB(1);

  // compute decomposition: t = qq(2b) | rg(4b) | bh(1b) | iseg(2b)
  const int iseg = t & 3;         // 4 floats of i each
  const int bh   = (t >> 2) & 1;  // b half
  const int rg   = (t >> 3) & 15; // 4 r each
  const int qq   = t >> 7;        // quadrant

  float acc[4][8];
#pragma unroll
  for (int k = 0; k < 4; ++k)
#pragma unroll
    for (int b = 0; b < 8; ++b) acc[k][b] = 0.0f;
  float res[2][4] = {{0.f, 0.f, 0.f, 0.f}, {0.f, 0.f, 0.f, 0.f}};

  // ---------- 16 projection phases (i16 slices) ----------
#pragma unroll
  for (int p = 0; p < 16; ++p) {
    // issue: x for p+1, slab for p+2 (p>=14 rolls into fo quarters 0,1)
    if (p < 15) ISSUE_X(p + 1);
    if (p < 14) ISSUE_SLAB(p + 2); else ISSUE_FO(p - 14);
    // steady state: w0-3 leave {S(p+1),X(p+1),S(p+2)}=5, w4-7 leave {S+S}=4.
    // p==15: both classes leave {FO0,FO1}=4.
    if (p < 15) {
      if (wid < 4) { WAITVM(5); } else { WAITVM(4); }
    } else {
      WAITVM(4);
    }
    BARRIER();

    const float* fb = s_fb + (p % 3) * 4096 + qq * 1024;
    const float* xb = s_xs + (p & 1) * 1024;
    float4 fv[4];
#pragma unroll
    for (int k = 0; k < 4; ++k)
      fv[k] = *(const float4*)(fb + (rg * 4 + k) * 16 + (iseg << 2));
    float4 xv[8];
#pragma unroll
    for (int b = 0; b < 8; ++b)
      xv[b] = *(const float4*)(xb + ((bh * 8 + b) * 4 + qq) * 16 + (iseg << 2));
#pragma unroll
    for (int k = 0; k < 4; ++k)
#pragma unroll
      for (int b = 0; b < 8; ++b) {
        acc[k][b] = fmaf(fv[k].x, xv[b].x, acc[k][b]);
        acc[k][b] = fmaf(fv[k].y, xv[b].y, acc[k][b]);
        acc[k][b] = fmaf(fv[k].z, xv[b].z, acc[k][b]);
        acc[k][b] = fmaf(fv[k].w, xv[b].w, acc[k][b]);
      }
    // residual: lanes owning o in [16p,16p+16) grab their 4q x this phase
    if ((lane >> 2) == p) {
#pragma unroll
      for (int bb = 0; bb < 2; ++bb)
#pragma unroll
        for (int q = 0; q < 4; ++q) {
          const float4 xq =
              *(const float4*)(xb + ((wid * 2 + bb) * 4 + q) * 16 + ((lane & 3) << 2));
          res[bb][0] += xq.x; res[bb][1] += xq.y;
          res[bb][2] += xq.z; res[bb][3] += xq.w;
        }
    }
    BARRIER(); // buffer-reuse fence: next phase's DMA overwrites slot (p)%3 / (p)%2
  }

  // fo quarter 2 into slot 0 (slab15's slot, freed by the barrier above)
  ISSUE_FO(2);

  // ---------- reduce over iseg, write P ----------
#pragma unroll
  for (int k = 0; k < 4; ++k)
#pragma unroll
    for (int b = 0; b < 8; ++b) {
      float v = acc[k][b];
      v += __shfl_xor(v, 1);
      v += __shfl_xor(v, 2);
      acc[k][b] = v;
    }
#pragma unroll
  for (int k = 0; k < 4; ++k) {
    if (iseg == k) { // static acc index (rule #20)
#pragma unroll
      for (int b = 0; b < 8; ++b)
        s_ps[qq * 1024 + (bh * 8 + b) * 64 + rg * 4 + k] = acc[k][b];
    }
  }
  LGKM0(); BARRIER();

  // ---------- RMS per (q,b) row ----------
#pragma unroll
  for (int j = 0; j < 8; ++j) {
    const int row = wid * 8 + j; // row = q*16 + b
    const float v = s_ps[row * 64 + lane];
    float ssum = v * v;
#pragma unroll
    for (int d = 1; d < 64; d <<= 1) ssum += __shfl_xor(ssum, d);
    if (lane == 0) s_rr[row] = 1.0f / sqrtf(ssum * (1.0f / 64.0f) + 1e-6f);
  }
  LGKM0(); BARRIER();

  // ---------- merged[b][r] -> s_ps plane 0 (element-owned, race-free) ----------
#pragma unroll
  for (int e0 = 0; e0 < 2; ++e0) {
    const int e = t + e0 * 512;
    const int b = e >> 6, r = e & 63;
    float m = gn;
#pragma unroll
    for (int q = 0; q < 4; ++q) m *= s_ps[q * 1024 + b * 64 + r] * s_rr[q * 16 + b];
    s_ps[b * 64 + r] = m;
  }

  // ---------- out GEMM over 4 fo quarters: thread = (2 b) x (4 o) ----------
  float oa[2][4] = {{0.f, 0.f, 0.f, 0.f}, {0.f, 0.f, 0.f, 0.f}};
#pragma unroll
  for (int h = 0; h < 4; ++h) {
    // outstanding: h0 {FO0,FO1,FO2}=6 need FO0; h1 {FO1,FO2,FO3}=6 need FO1;
    // h2 {FO2,FO3}=4 need FO2; h3 {FO3}=2 need FO3.
    if (h == 0)      { WAITVM(4); }
    else if (h == 1) { WAITVM(4); }
    else if (h == 2) { WAITVM(2); }
    else             { WAITVM(0); }
    BARRIER();
    const float* fsp = s_fb + ((16 + h) % 3) * 4096;
#pragma unroll
    for (int rr = 0; rr < 16; ++rr) {
      const float4 f4 = *(const float4*)(fsp + rr * 256 + (lane << 2));
      const float m0 = s_ps[(wid * 2 + 0) * 64 + h * 16 + rr];
      const float m1 = s_ps[(wid * 2 + 1) * 64 + h * 16 + rr];
      oa[0][0] = fmaf(m0, f4.x, oa[0][0]); oa[0][1] = fmaf(m0, f4.y, oa[0][1]);
      oa[0][2] = fmaf(m0, f4.z, oa[0][2]); oa[0][3] = fmaf(m0, f4.w, oa[0][3]);
      oa[1][0] = fmaf(m1, f4.x, oa[1][0]); oa[1][1] = fmaf(m1, f4.y, oa[1][1]);
      oa[1][2] = fmaf(m1, f4.z, oa[1][2]); oa[1][3] = fmaf(m1, f4.w, oa[1][3]);
    }
    if (h == 0) {
      BARRIER();    // all waves done reading slot1 (FO0)
      ISSUE_FO(3);  // FO3 -> slot1
    }
  }

  // ---------- store: out[b][n][o] = gemm + 0.25*sum_q x ----------
#pragma unroll
  for (int bb = 0; bb < 2; ++bb) {
    const int b = wid * 2 + bb;
    float4 o4;
    o4.x = oa[bb][0] + 0.25f * res[bb][0];
    o4.y = oa[bb][1] + 0.25f * res[bb][1];
    o4.z = oa[bb][2] + 0.25f * res[bb][2];
    o4.w = oa[bb][3] + 0.25f * res[bb][3];
    *(float4*)(out + ((size_t)b * NN + n) * 256 + (lane << 2)) = o4;
  }
}

extern "C" void kernel_launch(void* const* d_in, const int* in_sizes, int n_in,
                              void* d_out, int out_size, void* d_ws, size_t ws_size,
                              hipStream_t stream) {
  const float* x   = (const float*)d_in[0];
  const float* ftl = (const float*)d_in[1];
  const float* ftr = (const float*)d_in[2];
  const float* fbl = (const float*)d_in[3];
  const float* fbr = (const float*)d_in[4];
  const float* fo  = (const float*)d_in[5];
  const float* gn  = (const float*)d_in[6];
  float* o = (float*)d_out;
  cpquad_kernel<<<dim3(NN), dim3(512), 0, stream>>>(x, ftl, ftr, fbl, fbr, fo, gn, o);
}

// Round 3
// 1303.818 us; speedup vs baseline: 1.1766x; 1.1766x over previous
//
#include <hip/hip_runtime.h>
#include <math.h>

// CPQuadRankLayer: B=16, N=2048, IN=OUT=256, R=64, Q=4.
// out[b,n,o] = sum_r ( prod_q rmsnorm_r(x[b,n,q,:] @ Fq[n]^T) )[r] * gain[n] * Fo[n,r,o]
//              + mean_q x[b,n,q,o]
//
// One WG per n, 512 threads, 72.3 KB LDS, target 2 WG/CU.
// R2 post-mortem: __launch_bounds__(512,4) capped VGPR at 64 -> 3 GB of scratch
// spill traffic (WRITE_SIZE 33MB->3GB, 6.6x slower). Empirically arg2 acts as
// blocks/CU here: (512,2) -> 128-reg cap, which round 1 hit at 120 with no
// spill. Also: fv rows r=rg*4+k all shared r&1 -> 16-bank 8-way conflict
// (SQ_LDS_BANK_CONFLICT 2.1e7); remapped to r=k*16+rg so r&1 varies per lane.
//
// Factor stream: 20 x 16KB slabs per n (16 proj i16-slices + 4 fo quarters)
// through a 3-slot LDS ring via global_load_lds(16B); x as 4KB i16 chunks in a
// 2-slot buffer. Counted vmcnt (never 0 in the loop), raw s_barrier.

#define WAITVM(NLIT) asm volatile("s_waitcnt vmcnt(" #NLIT ") lgkmcnt(0)" ::: "memory")
#define LGKM0()      asm volatile("s_waitcnt lgkmcnt(0)" ::: "memory")
#define BARRIER()    __builtin_amdgcn_s_barrier()

__device__ __forceinline__ void g2l16(const float* g, float* l) {
  __builtin_amdgcn_global_load_lds(
      (const __attribute__((address_space(1))) void*)g,
      (__attribute__((address_space(3))) void*)l, 16, 0, 0);
}

#define NN 2048

__global__ __launch_bounds__(512, 2) void cpquad_kernel(
    const float* __restrict__ x,
    const float* __restrict__ ftl, const float* __restrict__ ftr,
    const float* __restrict__ fbl, const float* __restrict__ fbr,
    const float* __restrict__ fout, const float* __restrict__ gain,
    float* __restrict__ out) {

  // LDS: 12288 + 2048 + 4096 + 64 floats = 72.25 KB
  alignas(16) __shared__ float s_fb[3 * 4096]; // ring: proj slab [4q][64r][16i] / fo quarter [16r][256o]
  alignas(16) __shared__ float s_xs[2 * 1024]; // x i16 chunk dbuf: [64 c2=b*4+q][16 i]
  alignas(16) __shared__ float s_ps[4096];     // [4 q][16 b][64 r]; plane0 overwritten by merged
  __shared__ float s_rr[64];                   // [4 q][16 b] 1/rms

  const int t = threadIdx.x, lane = t & 63, wid = t >> 6;
  const int n = blockIdx.x;
  const float gn = gain[n];

  // ---------- staging sources ----------
  // proj slab chunk k2 (1KB, 64 lanes x 16B): c = wid*2+k2; q=c>>2; r=(c&3)*16+(lane>>2)
  const float* ss[2];
#pragma unroll
  for (int k2 = 0; k2 < 2; ++k2) {
    const int c = wid * 2 + k2, q = c >> 2, r = (c & 3) * 16 + (lane >> 2);
    const float* fq = (q == 0) ? ftl : ((q == 1) ? ftr : ((q == 2) ? fbl : fbr));
    ss[k2] = fq + ((size_t)n * 64 + r) * 256 + (lane & 3) * 4;
  }
  // x chunk (waves 0-3 only, 1KB): c2 = wid*16 + (lane>>2); b=c2>>2; qx=c2&3
  const int c2 = wid * 16 + (lane >> 2);
  const float* xsrc =
      x + (((size_t)(c2 >> 2) * NN + n) * 4 + (c2 & 3)) * 256 + (lane & 3) * 4;
  // fo quarter chunk k2: linear [16r][256o]
  const float* osrc = fout + (size_t)n * 16384 + wid * 512 + lane * 4;

  // ---------- issue helpers (wave-uniform LDS base; HW scatters lane*16B) ----------
  auto ISSUE_SLAB = [&](int s) {
    float* d = s_fb + (s % 3) * 4096 + wid * 512;
    g2l16(ss[0] + s * 16, d);
    g2l16(ss[1] + s * 16, d + 256);
  };
  auto ISSUE_X = [&](int p) {
    if (wid < 4) g2l16(xsrc + p * 16, s_xs + (p & 1) * 1024 + wid * 256);
  };
  auto ISSUE_FO = [&](int h) {
    float* d = s_fb + ((16 + h) % 3) * 4096 + wid * 512;
    g2l16(osrc + h * 4096, d);
    g2l16(osrc + h * 4096 + 256, d + 256);
  };

  // ---------- prologue: X0, S0, S1 (order matters for vmcnt counting) ----------
  ISSUE_X(0);
  ISSUE_SLAB(0);
  ISSUE_SLAB(1);

  // compute decomposition: t = qq(2b) | rg(4b) | bh(1b) | iseg(2b)
  const int iseg = t & 3;         // 4 floats of i each
  const int bh   = (t >> 2) & 1;  // b half
  const int rg   = (t >> 3) & 15; // base r; thread owns rows {rg, rg+16, rg+32, rg+48}
  const int qq   = t >> 7;        // quadrant

  float acc[4][8];
#pragma unroll
  for (int k = 0; k < 4; ++k)
#pragma unroll
    for (int b = 0; b < 8; ++b) acc[k][b] = 0.0f;
  float res[2][4] = {{0.f, 0.f, 0.f, 0.f}, {0.f, 0.f, 0.f, 0.f}};

  // ---------- 16 projection phases (i16 slices) ----------
#pragma unroll
  for (int p = 0; p < 16; ++p) {
    // issue: x for p+1, slab for p+2 (p>=14 rolls into fo quarters 0,1)
    if (p < 15) ISSUE_X(p + 1);
    if (p < 14) ISSUE_SLAB(p + 2); else ISSUE_FO(p - 14);
    // steady state: w0-3 leave {S(p+1),X(p+1),S(p+2)}=5, w4-7 leave {S+S}=4.
    // p==15: both classes leave {FO0,FO1}=4.
    if (p < 15) {
      if (wid < 4) { WAITVM(5); } else { WAITVM(4); }
    } else {
      WAITVM(4);
    }
    BARRIER();

    const float* fb = s_fb + (p % 3) * 4096 + qq * 1024;
    const float* xb = s_xs + (p & 1) * 1024;
    // rows r = k*16 + rg: r&1 = rg&1 varies across lanes -> full 32-bank spread
    float4 fv[4];
#pragma unroll
    for (int k = 0; k < 4; ++k)
      fv[k] = *(const float4*)(fb + (k * 16 + rg) * 16 + (iseg << 2));
    float4 xv[8];
#pragma unroll
    for (int b = 0; b < 8; ++b)
      xv[b] = *(const float4*)(xb + ((bh * 8 + b) * 4 + qq) * 16 + (iseg << 2));
#pragma unroll
    for (int k = 0; k < 4; ++k)
#pragma unroll
      for (int b = 0; b < 8; ++b) {
        acc[k][b] = fmaf(fv[k].x, xv[b].x, acc[k][b]);
        acc[k][b] = fmaf(fv[k].y, xv[b].y, acc[k][b]);
        acc[k][b] = fmaf(fv[k].z, xv[b].z, acc[k][b]);
        acc[k][b] = fmaf(fv[k].w, xv[b].w, acc[k][b]);
      }
    // residual: lanes owning o in [16p,16p+16) grab their 4q x this phase
    if ((lane >> 2) == p) {
#pragma unroll
      for (int bb = 0; bb < 2; ++bb)
#pragma unroll
        for (int q = 0; q < 4; ++q) {
          const float4 xq =
              *(const float4*)(xb + ((wid * 2 + bb) * 4 + q) * 16 + ((lane & 3) << 2));
          res[bb][0] += xq.x; res[bb][1] += xq.y;
          res[bb][2] += xq.z; res[bb][3] += xq.w;
        }
    }
    BARRIER(); // buffer-reuse fence: next phase's DMA overwrites slot (p)%3 / (p)%2
  }

  // fo quarter 2 into slot 0 (slab15's slot, freed by the barrier above)
  ISSUE_FO(2);

  // ---------- reduce over iseg, write P ----------
#pragma unroll
  for (int k = 0; k < 4; ++k)
#pragma unroll
    for (int b = 0; b < 8; ++b) {
      float v = acc[k][b];
      v += __shfl_xor(v, 1);
      v += __shfl_xor(v, 2);
      acc[k][b] = v;
    }
#pragma unroll
  for (int k = 0; k < 4; ++k) {
    if (iseg == k) { // static acc index (rule #20)
#pragma unroll
      for (int b = 0; b < 8; ++b)
        s_ps[qq * 1024 + (bh * 8 + b) * 64 + k * 16 + rg] = acc[k][b];
    }
  }
  LGKM0(); BARRIER();

  // ---------- RMS per (q,b) row ----------
#pragma unroll
  for (int j = 0; j < 8; ++j) {
    const int row = wid * 8 + j; // row = q*16 + b
    const float v = s_ps[row * 64 + lane];
    float ssum = v * v;
#pragma unroll
    for (int d = 1; d < 64; d <<= 1) ssum += __shfl_xor(ssum, d);
    if (lane == 0) s_rr[row] = 1.0f / sqrtf(ssum * (1.0f / 64.0f) + 1e-6f);
  }
  LGKM0(); BARRIER();

  // ---------- merged[b][r] -> s_ps plane 0 (element-owned, race-free) ----------
#pragma unroll
  for (int e0 = 0; e0 < 2; ++e0) {
    const int e = t + e0 * 512;
    const int b = e >> 6, r = e & 63;
    float m = gn;
#pragma unroll
    for (int q = 0; q < 4; ++q) m *= s_ps[q * 1024 + b * 64 + r] * s_rr[q * 16 + b];
    s_ps[b * 64 + r] = m;
  }

  // ---------- out GEMM over 4 fo quarters: thread = (2 b) x (4 o) ----------
  float oa[2][4] = {{0.f, 0.f, 0.f, 0.f}, {0.f, 0.f, 0.f, 0.f}};
#pragma unroll
  for (int h = 0; h < 4; ++h) {
    // outstanding: h0 {FO0,FO1,FO2}=6 need FO0; h1 {FO1,FO2,FO3}=6 need FO1;
    // h2 {FO2,FO3}=4 need FO2; h3 {FO3}=2 need FO3.
    if (h == 0)      { WAITVM(4); }
    else if (h == 1) { WAITVM(4); }
    else if (h == 2) { WAITVM(2); }
    else             { WAITVM(0); }
    BARRIER();
    const float* fsp = s_fb + ((16 + h) % 3) * 4096;
#pragma unroll
    for (int rr = 0; rr < 16; ++rr) {
      const float4 f4 = *(const float4*)(fsp + rr * 256 + (lane << 2));
      const float m0 = s_ps[(wid * 2 + 0) * 64 + h * 16 + rr];
      const float m1 = s_ps[(wid * 2 + 1) * 64 + h * 16 + rr];
      oa[0][0] = fmaf(m0, f4.x, oa[0][0]); oa[0][1] = fmaf(m0, f4.y, oa[0][1]);
      oa[0][2] = fmaf(m0, f4.z, oa[0][2]); oa[0][3] = fmaf(m0, f4.w, oa[0][3]);
      oa[1][0] = fmaf(m1, f4.x, oa[1][0]); oa[1][1] = fmaf(m1, f4.y, oa[1][1]);
      oa[1][2] = fmaf(m1, f4.z, oa[1][2]); oa[1][3] = fmaf(m1, f4.w, oa[1][3]);
    }
    if (h == 0) {
      BARRIER();    // all waves done reading slot1 (FO0)
      ISSUE_FO(3);  // FO3 -> slot1
    }
  }

  // ---------- store: out[b][n][o] = gemm + 0.25*sum_q x ----------
#pragma unroll
  for (int bb = 0; bb < 2; ++bb) {
    const int b = wid * 2 + bb;
    float4 o4;
    o4.x = oa[bb][0] + 0.25f * res[bb][0];
    o4.y = oa[bb][1] + 0.25f * res[bb][1];
    o4.z = oa[bb][2] + 0.25f * res[bb][2];
    o4.w = oa[bb][3] + 0.25f * res[bb][3];
    *(float4*)(out + ((size_t)b * NN + n) * 256 + (lane << 2)) = o4;
  }
}

extern "C" void kernel_launch(void* const* d_in, const int* in_sizes, int n_in,
                              void* d_out, int out_size, void* d_ws, size_t ws_size,
                              hipStream_t stream) {
  const float* x   = (const float*)d_in[0];
  const float* ftl = (const float*)d_in[1];
  const float* ftr = (const float*)d_in[2];
  const float* fbl = (const float*)d_in[3];
  const float* fbr = (const float*)d_in[4];
  const float* fo  = (const float*)d_in[5];
  const float* gn  = (const float*)d_in[6];
  float* o = (float*)d_out;
  cpquad_kernel<<<dim3(NN), dim3(512), 0, stream>>>(x, ftl, ftr, fbl, fbr, fo, gn, o);
}

// Round 4
// 1011.329 us; speedup vs baseline: 1.5169x; 1.2892x over previous
//
#include <hip/hip_runtime.h>
#include <math.h>

// CPQuadRankLayer: B=16, N=2048, IN=OUT=256, R=64, Q=4.
// out[b,n,o] = sum_r ( prod_q rmsnorm_r(x[b,n,q,:] @ Fq[n]^T) )[r] * gain[n] * Fo[n,r,o]
//              + mean_q x[b,n,q,o]
//
// One WG per n, 512 threads, 72.3 KB LDS, target 2 WG/CU (16 waves).
// R3 post-mortem: still spilling (WRITE 2.4GB) — the in-loop residual block's
// 32-reg load window overlapped the 48-reg fv/xv window -> peak ~140 > 128 cap.
// R4: residual moved to epilogue as a direct global re-read of x (8 coalesced
// dwordx4/thread, issued after all counted-vmcnt bookkeeping is done; latency
// hidden by the co-resident WG). Phase-loop peak ~100 regs.
//
// Factor stream: 20 x 16KB slabs per n (16 proj i16-slices + 4 fo quarters)
// through a 3-slot LDS ring via global_load_lds(16B); x as 4KB i16 chunks in a
// 2-slot buffer. Counted vmcnt (never 0 in the loop), raw s_barrier.

#define WAITVM(NLIT) asm volatile("s_waitcnt vmcnt(" #NLIT ") lgkmcnt(0)" ::: "memory")
#define LGKM0()      asm volatile("s_waitcnt lgkmcnt(0)" ::: "memory")
#define BARRIER()    __builtin_amdgcn_s_barrier()

__device__ __forceinline__ void g2l16(const float* g, float* l) {
  __builtin_amdgcn_global_load_lds(
      (const __attribute__((address_space(1))) void*)g,
      (__attribute__((address_space(3))) void*)l, 16, 0, 0);
}

#define NN 2048

__global__ __launch_bounds__(512, 2) void cpquad_kernel(
    const float* __restrict__ x,
    const float* __restrict__ ftl, const float* __restrict__ ftr,
    const float* __restrict__ fbl, const float* __restrict__ fbr,
    const float* __restrict__ fout, const float* __restrict__ gain,
    float* __restrict__ out) {

  // LDS: 12288 + 2048 + 4096 + 64 floats = 72.25 KB
  alignas(16) __shared__ float s_fb[3 * 4096]; // ring: proj slab [4q][64r][16i] / fo quarter [16r][256o]
  alignas(16) __shared__ float s_xs[2 * 1024]; // x i16 chunk dbuf: [64 c2=b*4+q][16 i]
  alignas(16) __shared__ float s_ps[4096];     // [4 q][16 b][64 r]; plane0 overwritten by merged
  __shared__ float s_rr[64];                   // [4 q][16 b] 1/rms

  const int t = threadIdx.x, lane = t & 63, wid = t >> 6;
  const int n = blockIdx.x;
  const float gn = gain[n];

  // ---------- staging sources ----------
  // proj slab chunk k2 (1KB, 64 lanes x 16B): c = wid*2+k2; q=c>>2; r=(c&3)*16+(lane>>2)
  const float* ss[2];
#pragma unroll
  for (int k2 = 0; k2 < 2; ++k2) {
    const int c = wid * 2 + k2, q = c >> 2, r = (c & 3) * 16 + (lane >> 2);
    const float* fq = (q == 0) ? ftl : ((q == 1) ? ftr : ((q == 2) ? fbl : fbr));
    ss[k2] = fq + ((size_t)n * 64 + r) * 256 + (lane & 3) * 4;
  }
  // x chunk (waves 0-3 only, 1KB): c2 = wid*16 + (lane>>2); b=c2>>2; qx=c2&3
  const int c2 = wid * 16 + (lane >> 2);
  const float* xsrc =
      x + (((size_t)(c2 >> 2) * NN + n) * 4 + (c2 & 3)) * 256 + (lane & 3) * 4;
  // fo quarter chunk k2: linear [16r][256o]
  const float* osrc = fout + (size_t)n * 16384 + wid * 512 + lane * 4;

  // ---------- issue helpers (wave-uniform LDS base; HW scatters lane*16B) ----------
  auto ISSUE_SLAB = [&](int s) {
    float* d = s_fb + (s % 3) * 4096 + wid * 512;
    g2l16(ss[0] + s * 16, d);
    g2l16(ss[1] + s * 16, d + 256);
  };
  auto ISSUE_X = [&](int p) {
    if (wid < 4) g2l16(xsrc + p * 16, s_xs + (p & 1) * 1024 + wid * 256);
  };
  auto ISSUE_FO = [&](int h) {
    float* d = s_fb + ((16 + h) % 3) * 4096 + wid * 512;
    g2l16(osrc + h * 4096, d);
    g2l16(osrc + h * 4096 + 256, d + 256);
  };

  // ---------- prologue: X0, S0, S1 (order matters for vmcnt counting) ----------
  ISSUE_X(0);
  ISSUE_SLAB(0);
  ISSUE_SLAB(1);

  // compute decomposition: t = qq(2b) | rg(4b) | bh(1b) | iseg(2b)
  const int iseg = t & 3;         // 4 floats of i each
  const int bh   = (t >> 2) & 1;  // b half
  const int rg   = (t >> 3) & 15; // base r; thread owns rows {rg, rg+16, rg+32, rg+48}
  const int qq   = t >> 7;        // quadrant

  float acc[4][8];
#pragma unroll
  for (int k = 0; k < 4; ++k)
#pragma unroll
    for (int b = 0; b < 8; ++b) acc[k][b] = 0.0f;

  // ---------- 16 projection phases (i16 slices) ----------
#pragma unroll
  for (int p = 0; p < 16; ++p) {
    // issue: x for p+1, slab for p+2 (p>=14 rolls into fo quarters 0,1)
    if (p < 15) ISSUE_X(p + 1);
    if (p < 14) ISSUE_SLAB(p + 2); else ISSUE_FO(p - 14);
    // steady state: w0-3 leave {S(p+1),X(p+1),S(p+2)}=5, w4-7 leave {S+S}=4.
    // p==15: both classes leave {FO0,FO1}=4.
    if (p < 15) {
      if (wid < 4) { WAITVM(5); } else { WAITVM(4); }
    } else {
      WAITVM(4);
    }
    BARRIER();

    const float* fb = s_fb + (p % 3) * 4096 + qq * 1024;
    const float* xb = s_xs + (p & 1) * 1024;
    // rows r = k*16 + rg: r&1 = rg&1 varies across lanes -> full 32-bank spread
    float4 fv[4];
#pragma unroll
    for (int k = 0; k < 4; ++k)
      fv[k] = *(const float4*)(fb + (k * 16 + rg) * 16 + (iseg << 2));
    float4 xv[8];
#pragma unroll
    for (int b = 0; b < 8; ++b)
      xv[b] = *(const float4*)(xb + ((bh * 8 + b) * 4 + qq) * 16 + (iseg << 2));
#pragma unroll
    for (int k = 0; k < 4; ++k)
#pragma unroll
      for (int b = 0; b < 8; ++b) {
        acc[k][b] = fmaf(fv[k].x, xv[b].x, acc[k][b]);
        acc[k][b] = fmaf(fv[k].y, xv[b].y, acc[k][b]);
        acc[k][b] = fmaf(fv[k].z, xv[b].z, acc[k][b]);
        acc[k][b] = fmaf(fv[k].w, xv[b].w, acc[k][b]);
      }
    LGKM0();   // reads of this phase's buffers complete before reuse
    BARRIER(); // buffer-reuse fence: next phase's DMA overwrites slot (p)%3 / (p)%2
  }

  // fo quarter 2 into slot 0 (slab15's slot, freed by the barrier above)
  ISSUE_FO(2);

  // ---------- reduce over iseg, write P ----------
#pragma unroll
  for (int k = 0; k < 4; ++k)
#pragma unroll
    for (int b = 0; b < 8; ++b) {
      float v = acc[k][b];
      v += __shfl_xor(v, 1);
      v += __shfl_xor(v, 2);
      acc[k][b] = v;
    }
#pragma unroll
  for (int k = 0; k < 4; ++k) {
    if (iseg == k) { // static acc index (rule #20)
#pragma unroll
      for (int b = 0; b < 8; ++b)
        s_ps[qq * 1024 + (bh * 8 + b) * 64 + k * 16 + rg] = acc[k][b];
    }
  }
  LGKM0(); BARRIER();

  // ---------- RMS per (q,b) row ----------
#pragma unroll
  for (int j = 0; j < 8; ++j) {
    const int row = wid * 8 + j; // row = q*16 + b
    const float v = s_ps[row * 64 + lane];
    float ssum = v * v;
#pragma unroll
    for (int d = 1; d < 64; d <<= 1) ssum += __shfl_xor(ssum, d);
    if (lane == 0) s_rr[row] = 1.0f / sqrtf(ssum * (1.0f / 64.0f) + 1e-6f);
  }
  LGKM0(); BARRIER();

  // ---------- merged[b][r] -> s_ps plane 0 (element-owned, race-free) ----------
#pragma unroll
  for (int e0 = 0; e0 < 2; ++e0) {
    const int e = t + e0 * 512;
    const int b = e >> 6, r = e & 63;
    float m = gn;
#pragma unroll
    for (int q = 0; q < 4; ++q) m *= s_ps[q * 1024 + b * 64 + r] * s_rr[q * 16 + b];
    s_ps[b * 64 + r] = m;
  }

  // ---------- out GEMM over 4 fo quarters: thread = (2 b) x (4 o) ----------
  float oa[2][4] = {{0.f, 0.f, 0.f, 0.f}, {0.f, 0.f, 0.f, 0.f}};
#pragma unroll
  for (int h = 0; h < 4; ++h) {
    // outstanding: h0 {FO0,FO1,FO2}=6 need FO0; h1 {FO1,FO2,FO3}=6 need FO1;
    // h2 {FO2,FO3}=4 need FO2; h3 {FO3}=2 need FO3.
    if (h == 0)      { WAITVM(4); }
    else if (h == 1) { WAITVM(4); }
    else if (h == 2) { WAITVM(2); }
    else             { WAITVM(0); }
    BARRIER();
    const float* fsp = s_fb + ((16 + h) % 3) * 4096;
#pragma unroll
    for (int rr = 0; rr < 16; ++rr) {
      const float4 f4 = *(const float4*)(fsp + rr * 256 + (lane << 2));
      const float m0 = s_ps[(wid * 2 + 0) * 64 + h * 16 + rr];
      const float m1 = s_ps[(wid * 2 + 1) * 64 + h * 16 + rr];
      oa[0][0] = fmaf(m0, f4.x, oa[0][0]); oa[0][1] = fmaf(m0, f4.y, oa[0][1]);
      oa[0][2] = fmaf(m0, f4.z, oa[0][2]); oa[0][3] = fmaf(m0, f4.w, oa[0][3]);
      oa[1][0] = fmaf(m1, f4.x, oa[1][0]); oa[1][1] = fmaf(m1, f4.y, oa[1][1]);
      oa[1][2] = fmaf(m1, f4.z, oa[1][2]); oa[1][3] = fmaf(m1, f4.w, oa[1][3]);
    }
    if (h == 0) {
      BARRIER();    // all waves done reading slot1 (FO0)
      ISSUE_FO(3);  // FO3 -> slot1
    }
  }

  // ---------- residual: re-read x (coalesced, likely L3-warm) ----------
  // All counted-vmcnt bookkeeping is complete (h3 drained to 0), so these
  // plain loads need no count adjustments; compiler inserts the dep waits.
  float4 xr[2][4];
#pragma unroll
  for (int bb = 0; bb < 2; ++bb)
#pragma unroll
    for (int q = 0; q < 4; ++q)
      xr[bb][q] = *(const float4*)(
          x + (((size_t)(wid * 2 + bb) * NN + n) * 4 + q) * 256 + (lane << 2));

  // ---------- store: out[b][n][o] = gemm + 0.25*sum_q x ----------
#pragma unroll
  for (int bb = 0; bb < 2; ++bb) {
    const int b = wid * 2 + bb;
    float4 o4;
    o4.x = oa[bb][0] + 0.25f * (xr[bb][0].x + xr[bb][1].x + xr[bb][2].x + xr[bb][3].x);
    o4.y = oa[bb][1] + 0.25f * (xr[bb][0].y + xr[bb][1].y + xr[bb][2].y + xr[bb][3].y);
    o4.z = oa[bb][2] + 0.25f * (xr[bb][0].z + xr[bb][1].z + xr[bb][2].z + xr[bb][3].z);
    o4.w = oa[bb][3] + 0.25f * (xr[bb][0].w + xr[bb][1].w + xr[bb][2].w + xr[bb][3].w);
    *(float4*)(out + ((size_t)b * NN + n) * 256 + (lane << 2)) = o4;
  }
}

extern "C" void kernel_launch(void* const* d_in, const int* in_sizes, int n_in,
                              void* d_out, int out_size, void* d_ws, size_t ws_size,
                              hipStream_t stream) {
  const float* x   = (const float*)d_in[0];
  const float* ftl = (const float*)d_in[1];
  const float* ftr = (const float*)d_in[2];
  const float* fbl = (const float*)d_in[3];
  const float* fbr = (const float*)d_in[4];
  const float* fo  = (const float*)d_in[5];
  const float* gn  = (const float*)d_in[6];
  float* o = (float*)d_out;
  cpquad_kernel<<<dim3(NN), dim3(512), 0, stream>>>(x, ftl, ftr, fbl, fbr, fo, gn, o);
}

// Round 5
// 200.208 us; speedup vs baseline: 7.6625x; 5.0514x over previous
//
#include <hip/hip_runtime.h>
#include <math.h>

// CPQuadRankLayer: B=16, N=2048, IN=OUT=256, R=64, Q=4.
// out[b,n,o] = sum_r ( prod_q rmsnorm_r(x[b,n,q,:] @ Fq[n]^T) )[r] * gain[n] * Fo[n,r,o]
//              + mean_q x[b,n,q,o]
//
// One WG per n, 512 threads, 72.3 KB LDS, 2 WG/CU target (128-reg cap).
// R4 post-mortem: WRITE 1.86GB of scratch spill at full 16x phase unroll —
// address hoisting across unrolled phases + an 80-reg fv/xv window exceeded
// the cap. R5: #pragma unroll 2 (kills address hoisting), xv split into two
// halves of 4 (window 64 regs), ss1 derived from ss0 (+16KB), plus the
// source-side XOR swizzle on proj slabs (8-way -> 4-way fv conflicts).
//
// Factor stream: 20 x 16KB slabs per n (16 proj i16-slices + 4 fo quarters)
// through a 3-slot LDS ring via global_load_lds(16B); x as 4KB i16 chunks in a
// 2-slot buffer. Counted vmcnt (never 0 in the loop), raw s_barrier.

#define WAITVM(NLIT) asm volatile("s_waitcnt vmcnt(" #NLIT ") lgkmcnt(0)" ::: "memory")
#define LGKM0()      asm volatile("s_waitcnt lgkmcnt(0)" ::: "memory")
#define BARRIER()    __builtin_amdgcn_s_barrier()

__device__ __forceinline__ void g2l16(const float* g, float* l) {
  __builtin_amdgcn_global_load_lds(
      (const __attribute__((address_space(1))) void*)g,
      (__attribute__((address_space(3))) void*)l, 16, 0, 0);
}

#define NN 2048

__global__ __launch_bounds__(512, 2) void cpquad_kernel(
    const float* __restrict__ x,
    const float* __restrict__ ftl, const float* __restrict__ ftr,
    const float* __restrict__ fbl, const float* __restrict__ fbr,
    const float* __restrict__ fout, const float* __restrict__ gain,
    float* __restrict__ out) {

  // LDS: 12288 + 2048 + 4096 + 64 floats = 72.25 KB
  alignas(16) __shared__ float s_fb[3 * 4096]; // ring: proj slab [4q][64r][16i] / fo quarter [16r][256o]
  alignas(16) __shared__ float s_xs[2 * 1024]; // x i16 chunk dbuf: [64 c2=b*4+q][16 i]
  alignas(16) __shared__ float s_ps[4096];     // [4 q][16 b][64 r]; plane0 overwritten by merged
  __shared__ float s_rr[64];                   // [4 q][16 b] 1/rms

  const int t = threadIdx.x, lane = t & 63, wid = t >> 6;
  const int n = blockIdx.x;
  const float gn = gain[n];

  // ---------- staging sources ----------
  // proj slab: wave w stages quadrant q=w>>1, rows r0=(w&1)*32+(lane>>2) and
  // r0+16. Source 16B slot is XOR-swizzled by f(r)=(r>>1)&3=(lane>>3)&3 so the
  // compute-side swizzled ds_read_b128 is conflict-reduced (LDS dest linear,
  // as global_load_lds requires; swizzle lives on the global source — rule:
  // both-sides-or-neither).
  const int q0 = wid >> 1;
  const int r0 = (wid & 1) * 32 + (lane >> 2);
  const float* fq0 = (q0 == 0) ? ftl : ((q0 == 1) ? ftr : ((q0 == 2) ? fbl : fbr));
  const float* ss0 =
      fq0 + ((size_t)n * 64 + r0) * 256 + (((lane & 3) ^ ((lane >> 3) & 3)) << 2);
  // x chunk (waves 0-3 only, 1KB): c2 = wid*16 + (lane>>2); b=c2>>2; qx=c2&3
  const int c2 = wid * 16 + (lane >> 2);
  const float* xsrc =
      x + (((size_t)(c2 >> 2) * NN + n) * 4 + (c2 & 3)) * 256 + (lane & 3) * 4;
  // fo quarter chunk: linear [16r][256o]
  const float* osrc = fout + (size_t)n * 16384 + wid * 512 + lane * 4;

  // ---------- issue helpers (wave-uniform LDS base; HW scatters lane*16B) ----------
  auto ISSUE_SLAB = [&](int s) {
    float* d = s_fb + (s % 3) * 4096 + wid * 512;
    g2l16(ss0 + s * 16, d);          // rows r0    (chunk k2=0)
    g2l16(ss0 + 4096 + s * 16, d + 256); // rows r0+16 (chunk k2=1, +16*256 floats)
  };
  auto ISSUE_X = [&](int p) {
    if (wid < 4) g2l16(xsrc + p * 16, s_xs + (p & 1) * 1024 + wid * 256);
  };
  auto ISSUE_FO = [&](int h) {
    float* d = s_fb + ((16 + h) % 3) * 4096 + wid * 512;
    g2l16(osrc + h * 4096, d);
    g2l16(osrc + h * 4096 + 256, d + 256);
  };

  // ---------- prologue: X0, S0, S1 (order matters for vmcnt counting) ----------
  ISSUE_X(0);
  ISSUE_SLAB(0);
  ISSUE_SLAB(1);

  // compute decomposition: t = qq(2b) | rg(4b) | bh(1b) | iseg(2b)
  const int iseg = t & 3;         // 4 floats of i each
  const int bh   = (t >> 2) & 1;  // b half
  const int rg   = (t >> 3) & 15; // base r; thread owns rows {rg, rg+16, rg+32, rg+48}
  const int qq   = t >> 7;        // quadrant
  const int fsl  = (iseg ^ ((rg >> 1) & 3)) << 2; // swizzled fv slot (floats)

  float acc[4][8];
#pragma unroll
  for (int k = 0; k < 4; ++k)
#pragma unroll
    for (int b = 0; b < 8; ++b) acc[k][b] = 0.0f;

  // ---------- 16 projection phases (i16 slices) ----------
  // unroll 2 (not 16): full unroll hoists many phases' staging/ds addresses
  // into registers -> spill (R4's 1.86GB scratch). Memory motion across
  // phases is already fenced by the asm "memory" clobbers.
#pragma unroll 2
  for (int p = 0; p < 16; ++p) {
    // issue: x for p+1, slab for p+2 (p>=14 rolls into fo quarters 0,1)
    if (p < 15) ISSUE_X(p + 1);
    if (p < 14) ISSUE_SLAB(p + 2); else ISSUE_FO(p - 14);
    // steady state: w0-3 leave {S(p+1),X(p+1),S(p+2)}=5, w4-7 leave {S+S}=4.
    // p==15: both classes leave {FO0,FO1}=4.
    if (p < 15) {
      if (wid < 4) { WAITVM(5); } else { WAITVM(4); }
    } else {
      WAITVM(4);
    }
    BARRIER();

    const float* fb = s_fb + (p % 3) * 4096 + qq * 1024;
    const float* xb = s_xs + (p & 1) * 1024;
    // rows r = k*16 + rg, swizzled slot: LDS[r][s] holds G[r][s ^ ((r>>1)&3)]
    float4 fv[4];
#pragma unroll
    for (int k = 0; k < 4; ++k)
      fv[k] = *(const float4*)(fb + (k * 16 + rg) * 16 + fsl);
    // xv in two halves of 4 to keep the live window at fv16+xv16+acc32
#pragma unroll
    for (int h2 = 0; h2 < 2; ++h2) {
      float4 xv[4];
#pragma unroll
      for (int bb = 0; bb < 4; ++bb)
        xv[bb] = *(const float4*)(xb + ((bh * 8 + h2 * 4 + bb) * 4 + qq) * 16 + (iseg << 2));
#pragma unroll
      for (int k = 0; k < 4; ++k)
#pragma unroll
        for (int bb = 0; bb < 4; ++bb) {
          acc[k][h2 * 4 + bb] = fmaf(fv[k].x, xv[bb].x, acc[k][h2 * 4 + bb]);
          acc[k][h2 * 4 + bb] = fmaf(fv[k].y, xv[bb].y, acc[k][h2 * 4 + bb]);
          acc[k][h2 * 4 + bb] = fmaf(fv[k].z, xv[bb].z, acc[k][h2 * 4 + bb]);
          acc[k][h2 * 4 + bb] = fmaf(fv[k].w, xv[bb].w, acc[k][h2 * 4 + bb]);
        }
    }
    LGKM0();   // this phase's ds_reads complete before the slot is re-DMA'd
    BARRIER(); // buffer-reuse fence
  }

  // fo quarter 2 into slot 0 (slab15's slot, freed by the barrier above)
  ISSUE_FO(2);

  // ---------- reduce over iseg, write P ----------
#pragma unroll
  for (int k = 0; k < 4; ++k)
#pragma unroll
    for (int b = 0; b < 8; ++b) {
      float v = acc[k][b];
      v += __shfl_xor(v, 1);
      v += __shfl_xor(v, 2);
      acc[k][b] = v;
    }
#pragma unroll
  for (int k = 0; k < 4; ++k) {
    if (iseg == k) { // static acc index (rule #20)
#pragma unroll
      for (int b = 0; b < 8; ++b)
        s_ps[qq * 1024 + (bh * 8 + b) * 64 + k * 16 + rg] = acc[k][b];
    }
  }
  LGKM0(); BARRIER();

  // ---------- RMS per (q,b) row ----------
#pragma unroll
  for (int j = 0; j < 8; ++j) {
    const int row = wid * 8 + j; // row = q*16 + b
    const float v = s_ps[row * 64 + lane];
    float ssum = v * v;
#pragma unroll
    for (int d = 1; d < 64; d <<= 1) ssum += __shfl_xor(ssum, d);
    if (lane == 0) s_rr[row] = 1.0f / sqrtf(ssum * (1.0f / 64.0f) + 1e-6f);
  }
  LGKM0(); BARRIER();

  // ---------- merged[b][r] -> s_ps plane 0 (element-owned, race-free) ----------
#pragma unroll
  for (int e0 = 0; e0 < 2; ++e0) {
    const int e = t + e0 * 512;
    const int b = e >> 6, r = e & 63;
    float m = gn;
#pragma unroll
    for (int q = 0; q < 4; ++q) m *= s_ps[q * 1024 + b * 64 + r] * s_rr[q * 16 + b];
    s_ps[b * 64 + r] = m;
  }

  // ---------- out GEMM over 4 fo quarters: thread = (2 b) x (4 o) ----------
  float oa[2][4] = {{0.f, 0.f, 0.f, 0.f}, {0.f, 0.f, 0.f, 0.f}};
#pragma unroll
  for (int h = 0; h < 4; ++h) {
    // outstanding: h0 {FO0,FO1,FO2}=6 need FO0; h1 {FO1,FO2,FO3}=6 need FO1;
    // h2 {FO2,FO3}=4 need FO2; h3 {FO3}=2 need FO3.
    if (h == 0)      { WAITVM(4); }
    else if (h == 1) { WAITVM(4); }
    else if (h == 2) { WAITVM(2); }
    else             { WAITVM(0); }
    BARRIER();
    const float* fsp = s_fb + ((16 + h) % 3) * 4096;
#pragma unroll
    for (int rr = 0; rr < 16; ++rr) {
      const float4 f4 = *(const float4*)(fsp + rr * 256 + (lane << 2));
      const float m0 = s_ps[(wid * 2 + 0) * 64 + h * 16 + rr];
      const float m1 = s_ps[(wid * 2 + 1) * 64 + h * 16 + rr];
      oa[0][0] = fmaf(m0, f4.x, oa[0][0]); oa[0][1] = fmaf(m0, f4.y, oa[0][1]);
      oa[0][2] = fmaf(m0, f4.z, oa[0][2]); oa[0][3] = fmaf(m0, f4.w, oa[0][3]);
      oa[1][0] = fmaf(m1, f4.x, oa[1][0]); oa[1][1] = fmaf(m1, f4.y, oa[1][1]);
      oa[1][2] = fmaf(m1, f4.z, oa[1][2]); oa[1][3] = fmaf(m1, f4.w, oa[1][3]);
    }
    if (h == 0) {
      BARRIER();    // all waves done reading slot1 (FO0)
      ISSUE_FO(3);  // FO3 -> slot1
    }
  }

  // ---------- residual: re-read x (coalesced, L3/L2-warm from staging) ----------
  // All counted-vmcnt bookkeeping is drained (h3 -> vmcnt 0); plain loads here
  // need no count adjustments.
#pragma unroll
  for (int bb = 0; bb < 2; ++bb) {
    const int b = wid * 2 + bb;
    const float* xe = x + (((size_t)b * NN + n) * 4) * 256 + (lane << 2);
    float4 x0 = *(const float4*)(xe);
    float4 x1 = *(const float4*)(xe + 256);
    float4 x2 = *(const float4*)(xe + 512);
    float4 x3 = *(const float4*)(xe + 768);
    float4 o4;
    o4.x = oa[bb][0] + 0.25f * (x0.x + x1.x + x2.x + x3.x);
    o4.y = oa[bb][1] + 0.25f * (x0.y + x1.y + x2.y + x3.y);
    o4.z = oa[bb][2] + 0.25f * (x0.z + x1.z + x2.z + x3.z);
    o4.w = oa[bb][3] + 0.25f * (x0.w + x1.w + x2.w + x3.w);
    *(float4*)(out + ((size_t)b * NN + n) * 256 + (lane << 2)) = o4;
  }
}

extern "C" void kernel_launch(void* const* d_in, const int* in_sizes, int n_in,
                              void* d_out, int out_size, void* d_ws, size_t ws_size,
                              hipStream_t stream) {
  const float* x   = (const float*)d_in[0];
  const float* ftl = (const float*)d_in[1];
  const float* ftr = (const float*)d_in[2];
  const float* fbl = (const float*)d_in[3];
  const float* fbr = (const float*)d_in[4];
  const float* fo  = (const float*)d_in[5];
  const float* gn  = (const float*)d_in[6];
  float* o = (float*)d_out;
  cpquad_kernel<<<dim3(NN), dim3(512), 0, stream>>>(x, ftl, ftr, fbl, fbr, fo, gn, o);
}